// Round 12
// baseline (189.876 us; speedup 1.0000x reference)
//
#include <hip/hip_runtime.h>
#include <hip/hip_bf16.h>

typedef _Float16 f16;
typedef _Float16 f16x8 __attribute__((ext_vector_type(8)));
typedef _Float16 f16x4 __attribute__((ext_vector_type(4)));
typedef float    f32x4 __attribute__((ext_vector_type(4)));

#define DEV __device__ __forceinline__

DEV f16x8 load16(const void* p) {
  return __builtin_bit_cast(f16x8, *(const uint4*)p);
}
DEV f32x4 mfma(f16x8 a, f16x8 b, f32x4 c) {
  return __builtin_amdgcn_mfma_f32_16x16x32_f16(a, b, c, 0, 0, 0);
}
DEV void async_cp16(void* lds_dst, const void* gsrc) {
  __builtin_amdgcn_global_load_lds(
      (const __attribute__((address_space(1))) void*)gsrc,
      (__attribute__((address_space(3))) void*)lds_dst,
      16, 0, 0);
}
DEV int pk2(float a, float b) {
  return __builtin_bit_cast(int, __builtin_amdgcn_cvt_pkrtz(a, b));
}
DEV int bperm(int lane_times4, int v) {
  return __builtin_amdgcn_ds_bpermute(lane_times4, v);
}

// ---------------- convert x -> f16 ----------------
__global__ __launch_bounds__(256) void k_cvt_x(const float4* __restrict__ x,
                                               f16x4* __restrict__ xf) {
  int gid = blockIdx.x * 256 + threadIdx.x;   // 1048576 exact
  float4 v = x[gid];
  f16x4 h = {(f16)v.x, (f16)v.y, (f16)v.z, (f16)v.w};
  xf[gid] = h;
}

// ---------------- convert + transpose W: WT[n][k] f16 ----------------
__global__ __launch_bounds__(256) void k_cvt_w(
    const float* __restrict__ Wq, const float* __restrict__ Wk, const float* __restrict__ Wv,
    f16* __restrict__ WqT, f16* __restrict__ WkT, f16* __restrict__ WvT) {
  int z = blockIdx.z;
  const float* W = (z == 0) ? Wq : (z == 1) ? Wk : Wv;
  f16* O = (z == 0) ? WqT : (z == 1) ? WkT : WvT;
  int t = blockIdx.x * 256 + threadIdx.x;  // 131072 exact
  int n = t & 255, k = t >> 8;
  O[n * 512 + k] = (f16)W[k * 256 + n];
}

// ---------------- fused projection GEMM: Q,K,V share the A(x) tile ----------------
// BM=64, BN=64; 512 blocks (128 m x 4 n), 2 blocks/CU; waves 1x4 (wave = n-col block)
// V accumulated with swapped operands -> emitted transposed as Vt[b][u][t]
__global__ __launch_bounds__(256, 2) void k_proj(
    const f16* __restrict__ xf,
    const f16* __restrict__ WqT, const f16* __restrict__ WkT, const f16* __restrict__ WvT,
    f16* __restrict__ Qf, f16* __restrict__ Kf, f16* __restrict__ Vt) {
  __shared__ __align__(16) unsigned char smem[65536];  // 2 x (A 8KB + 3xB 8KB)

  const int m0 = blockIdx.x * 64;
  const int n0 = blockIdx.y * 64;
  const int tid = threadIdx.x;
  const int w = tid >> 6, l = tid & 63;
  const int lr = l & 15, lg = l >> 4;

  f32x4 acc[3][4] = {};   // [gemm z][m-frag]

  const unsigned char* Ab = (const unsigned char*)xf;
  const unsigned char* Wb[3] = {(const unsigned char*)WqT, (const unsigned char*)WkT,
                                (const unsigned char*)WvT};

  auto STAGE = [&](int kt, int bufo) {
    const int k0b = kt * 128;  // 64 f16 = 128B per k-block
    const int swz = ((l & 7) * 16) ^ ((l >> 3) << 4);
    if (w == 0) {              // wave 0: A tile [64][64] = 8 chunks of 1KB
#pragma unroll
      for (int c = 0; c < 8; ++c) {
        int row = c * 8 + (l >> 3);
        async_cp16(smem + bufo + c * 1024,
                   Ab + (size_t)(m0 + row) * 1024 + k0b + swz);
      }
    } else {                   // wave g+1: B tile for gemm g, 8 chunks
      const unsigned char* Bg = Wb[w - 1];
#pragma unroll
      for (int c = 0; c < 8; ++c) {
        int row = c * 8 + (l >> 3);
        async_cp16(smem + bufo + 8192 + (w - 1) * 8192 + c * 1024,
                   Bg + (size_t)(n0 + row) * 1024 + k0b + swz);
      }
    }
  };

  STAGE(0, 0);
  __syncthreads();

  for (int kt = 0; kt < 8; ++kt) {
    const int cur = (kt & 1) << 15;
    if (kt < 7) STAGE(kt + 1, cur ^ 32768);
    const unsigned char* ldsA = smem + cur;
    const unsigned char* ldsB = smem + cur + 8192;
#pragma unroll
    for (int ks = 0; ks < 2; ++ks) {
      const int colb = ks * 64 + lg * 16;
      f16x8 af[4], bf[3];
#pragma unroll
      for (int mb = 0; mb < 4; ++mb) {
        int row = mb * 16 + lr;
        af[mb] = load16(ldsA + row * 128 + (colb ^ ((row & 7) << 4)));
      }
      {
        int row = w * 16 + lr;
        int off = row * 128 + (colb ^ ((row & 7) << 4));
#pragma unroll
        for (int g = 0; g < 3; ++g) bf[g] = load16(ldsB + g * 8192 + off);
      }
#pragma unroll
      for (int mb = 0; mb < 4; ++mb) {
        acc[0][mb] = mfma(af[mb], bf[0], acc[0][mb]);
        acc[1][mb] = mfma(af[mb], bf[1], acc[1][mb]);
        acc[2][mb] = mfma(bf[2], af[mb], acc[2][mb]);   // swapped: D[u][t]
      }
    }
    __syncthreads();
  }

  // epilogue
#pragma unroll
  for (int mb = 0; mb < 4; ++mb)
#pragma unroll
    for (int j = 0; j < 4; ++j) {
      int row = m0 + mb * 16 + lg * 4 + j;
      int col = n0 + w * 16 + lr;
      Qf[(size_t)row * 256 + col] = (f16)acc[0][mb][j];
      Kf[(size_t)row * 256 + col] = (f16)acc[1][mb][j];
    }
  {
    const int bb = m0 >> 11;
    const int tl0 = m0 & 2047;
#pragma unroll
    for (int mb = 0; mb < 4; ++mb)
#pragma unroll
      for (int j = 0; j < 4; ++j) {
        int u  = n0 + w * 16 + lg * 4 + j;
        int tg = tl0 + mb * 16 + lr;
        Vt[((size_t)bb * 256 + u) * 2048 + tg] = (f16)acc[2][mb][j];
      }
  }
}

// ---------------- flash attention, f16, swapped-QK, 8-way KV split ----------------
// 1024 blocks: idx -> (chunk = b*8+qq, qt); QBLK=64, KVBLK=32, 8 iters
// K double-buffered in LDS (32KB); V read direct from global (L2-resident)
__global__ __launch_bounds__(256, 4) void k_attn(
    const f16* __restrict__ Qf, const f16* __restrict__ Kf, const f16* __restrict__ Vt,
    f16* __restrict__ pO, float* __restrict__ pm, float* __restrict__ pl) {
  __shared__ __align__(16) unsigned char smem[32768];  // 2 x K 16KB

  const int phys = blockIdx.x;
  const int idx  = (phys & 7) * 128 + (phys >> 3);   // bijective XCD swizzle (1024 = 8*128)
  const int chunk = idx >> 5, qt = idx & 31;
  const int b = chunk >> 3, qq = chunk & 7;
  const int q0 = qt * 64;
  const int tbase = qq * 256;

  const int tid = threadIdx.x, w = tid >> 6, l = tid & 63;
  const int lr = l & 15, lg = l >> 4;

  // Q fragments resident (B-operand of swapped QK): Q[q = w*16+lr][u = ks*32+lg*8..]
  f16x8 qh[8];
  {
    const f16* qrow = Qf + (size_t)(b * 2048 + q0 + w * 16 + lr) * 256;
#pragma unroll
    for (int ks = 0; ks < 8; ++ks) qh[ks] = load16(qrow + ks * 32 + lg * 8);
  }

  f32x4 acc[16] = {};
  float mrun = -__builtin_inff(), lrun = 0.f;   // stats for q = lr (uniform over lg)

  const unsigned char* Kb = (const unsigned char*)Kf + (size_t)b * 2048 * 512;
  const unsigned char* Vb = (const unsigned char*)Vt + (size_t)b * 256 * 4096;

  auto STAGE = [&](int it, int bufo) {
    const int t0 = tbase + it * 32;
#pragma unroll
    for (int ii = 0; ii < 4; ++ii) {    // K tile [32][256] f16 = 16 x 1KB, wave does 4
      int c = w * 4 + ii;
      int row = c * 2 + (l >> 5);
      async_cp16(smem + bufo + c * 1024,
                 Kb + (size_t)(t0 + row) * 512 + (((l & 31) * 16) ^ ((row & 7) << 4)));
    }
  };

  STAGE(0, 0);
  __syncthreads();

  for (int it = 0; it < 8; ++it) {
    const int cur = (it & 1) << 14;
    if (it < 7) STAGE(it + 1, cur ^ 16384);
    const unsigned char* ldsK = smem + cur;
    const int t0 = tbase + it * 32;
    const unsigned char* Vit = Vb + (size_t)t0 * 2 + lg * 16;  // V[ru][t0 + lg*8..]

    // S = K Q^T (swapped): lane holds S[t = lg*4+j (+16)][q = lr]
    f32x4 s0 = {}, s1 = {};
    const int sw = (lr & 7) << 4;
#pragma unroll
    for (int ks = 0; ks < 8; ++ks) {
      const int colb = ks * 64 + lg * 16;
      f16x8 k0 = load16(ldsK + lr * 512 + (colb ^ sw));
      f16x8 k1 = load16(ldsK + (16 + lr) * 512 + (colb ^ sw));
      s0 = mfma(k0, qh[ks], s0);
      s1 = mfma(k1, qh[ks], s1);
    }

    // in-register online softmax (8 vals/lane), defer-max THR=5
    float mt = fmaxf(fmaxf(fmaxf(s0[0], s0[1]), fmaxf(s0[2], s0[3])),
                     fmaxf(fmaxf(s1[0], s1[1]), fmaxf(s1[2], s1[3])));
    mt = fmaxf(mt, __shfl_xor(mt, 16, 64));
    mt = fmaxf(mt, __shfl_xor(mt, 32, 64));
    const bool need = !__all(mt <= mrun + 5.f);
    float al = 1.f;
    if (need) {                  // wave-uniform branch (from __all)
      float mn = fmaxf(mrun, mt);
      al = __expf(mrun - mn);
      mrun = mn;
    }
    float p0[4], p1[4];
#pragma unroll
    for (int j = 0; j < 4; ++j) {
      p0[j] = __expf(s0[j] - mrun);
      p1[j] = __expf(s1[j] - mrun);
    }
    float rs = (p0[0] + p0[1]) + (p0[2] + p0[3]) + (p1[0] + p1[1]) + (p1[2] + p1[3]);
    rs += __shfl_xor(rs, 16, 64);
    rs += __shfl_xor(rs, 32, 64);
    lrun = al * lrun + rs;

    if (need) {     // rescale acc: gather al for q = lg*4+j from lane (lg*4+j)
      float alj[4];
#pragma unroll
      for (int j = 0; j < 4; ++j)
        alj[j] = __builtin_bit_cast(float, bperm((lg * 4 + j) * 4, __builtin_bit_cast(int, al)));
#pragma unroll
      for (int nb = 0; nb < 16; ++nb) {
        f32x4 a = acc[nb];
        a[0] *= alj[0]; a[1] *= alj[1]; a[2] *= alj[2]; a[3] *= alj[3];
        acc[nb] = a;
      }
    }

    // P redistribution to PV A-frag via bpermute (all at full exec; cndmask after)
    int a0 = pk2(p0[0], p0[1]), a1 = pk2(p0[2], p0[3]);
    int b0 = pk2(p1[0], p1[1]), b1 = pk2(p1[2], p1[3]);
    const int srcA = (lr + ((lg & 1) ? 32 : 0)) * 4;
    const int srcB = srcA + 64;
    int ta0 = bperm(srcA, a0), ta1 = bperm(srcA, a1);
    int tb0 = bperm(srcA, b0), tb1 = bperm(srcA, b1);
    int ua0 = bperm(srcB, a0), ua1 = bperm(srcB, a1);
    int ub0 = bperm(srcB, b0), ub1 = bperm(srcB, b1);
    const bool useb = lg >= 2;
    int d0 = useb ? tb0 : ta0;
    int d1 = useb ? tb1 : ta1;
    int d2 = useb ? ub0 : ua0;
    int d3 = useb ? ub1 : ua1;
    int4 dv = {d0, d1, d2, d3};
    f16x8 pa = __builtin_bit_cast(f16x8, dv);

    // O += P V   (V B-operand fragments straight from global; L1/L2-resident)
#pragma unroll
    for (int nb = 0; nb < 16; ++nb) {
      int ru = nb * 16 + lr;
      f16x8 vf = load16(Vit + (size_t)ru * 4096);
      acc[nb] = mfma(pa, vf, acc[nb]);
    }

    __syncthreads();   // prefetch drained; buf[cur] free; next tile ready
  }

  // write partials (pO f16)
  const size_t prow = (size_t)idx * 64 + w * 16;
#pragma unroll
  for (int nb = 0; nb < 16; ++nb)
#pragma unroll
    for (int j = 0; j < 4; ++j)
      pO[(prow + lg * 4 + j) * 256 + nb * 16 + lr] = (f16)acc[nb][j];
  if (l < 16) {
    pm[prow + lr] = mrun;
    pl[prow + lr] = lrun;
  }
}

// ---------------- combine the 8 KV-split partials ----------------
__global__ __launch_bounds__(256) void k_combine(
    const f16* __restrict__ pO, const float* __restrict__ pm, const float* __restrict__ pl,
    float* __restrict__ out) {
  int gid = blockIdx.x * 256 + threadIdx.x;  // 8192*64 exact (4 u-values per thread)
  int gr = gid >> 6, uq = gid & 63;
  int b = gr >> 11, r = gr & 2047;
  int qt = r >> 6, rr = r & 63;
  float mv[8];
#pragma unroll
  for (int q = 0; q < 8; ++q)
    mv[q] = pm[(size_t)((b * 8 + q) * 32 + qt) * 64 + rr];
  float m = fmaxf(fmaxf(fmaxf(mv[0], mv[1]), fmaxf(mv[2], mv[3])),
                  fmaxf(fmaxf(mv[4], mv[5]), fmaxf(mv[6], mv[7])));
  float lsum = 0.f, wq[8];
#pragma unroll
  for (int q = 0; q < 8; ++q) {
    wq[q] = __expf(mv[q] - m);
    lsum += wq[q] * pl[(size_t)((b * 8 + q) * 32 + qt) * 64 + rr];
  }
  f32x4 o = {};
#pragma unroll
  for (int q = 0; q < 8; ++q) {
    const f16x4 hv = *(const f16x4*)(pO + ((size_t)((b * 8 + q) * 32 + qt) * 64 + rr) * 256 + uq * 4);
    f32x4 v = {(float)hv[0], (float)hv[1], (float)hv[2], (float)hv[3]};
    o += v * wq[q];
  }
  f32x4 res = o * (1.0f / lsum);
  *(f32x4*)(out + (size_t)gr * 256 + uq * 4) = res;
}

extern "C" void kernel_launch(void* const* d_in, const int* in_sizes, int n_in,
                              void* d_out, int out_size, void* d_ws, size_t ws_size,
                              hipStream_t stream) {
  const float* x  = (const float*)d_in[0];
  const float* Wq = (const float*)d_in[1];
  const float* Wk = (const float*)d_in[2];
  const float* Wv = (const float*)d_in[3];
  float* out = (float*)d_out;

  unsigned char* ws = (unsigned char*)d_ws;
  f16*   xf  = (f16*)(ws + 0);             // 8.39 MB
  f16*   WqT = (f16*)(ws + 8388608);       // 256 KB each
  f16*   WkT = (f16*)(ws + 8650752);
  f16*   WvT = (f16*)(ws + 8912896);
  f16*   Qf  = (f16*)(ws + 9175040);       // 4.19 MB each
  f16*   Kf  = (f16*)(ws + 13369344);
  f16*   Vt  = (f16*)(ws + 17563648);
  f16*   pO  = (f16*)(ws + 21757952);      // 33.55 MB (1024*64 rows x 256 f16)
  float* pm  = (float*)(ws + 55312384);    // 256 KB
  float* pl  = (float*)(ws + 55574528);    // end ~55.8 MB

  k_cvt_x<<<4096, 256, 0, stream>>>((const float4*)x, (f16x4*)xf);
  k_cvt_w<<<dim3(512, 1, 3), 256, 0, stream>>>(Wq, Wk, Wv, WqT, WkT, WvT);
  k_proj<<<dim3(128, 4), 256, 0, stream>>>(xf, WqT, WkT, WvT, Qf, Kf, Vt);
  k_attn<<<1024, 256, 0, stream>>>(Qf, Kf, Vt, pO, pm, pl);
  k_combine<<<2048, 256, 0, stream>>>(pO, pm, pl, out);
}